// Round 7
// baseline (550.198 us; speedup 1.0000x reference)
//
#include <hip/hip_runtime.h>
#include <hip/hip_bf16.h>

#define HID 128
#define CAP 64   // bucket capacity: deg ~ Poisson(16), P(any node >= 64) ~ 1e-14
#define NBK 2048 // scatter blocks in k_prep
#define NBL 1563 // layer-kernel blocks: ceil(3125 tiles / 2)

typedef __attribute__((ext_vector_type(8))) short bfrag;   // 8 bf16 = 4 VGPR
typedef __attribute__((ext_vector_type(4))) float f32x4;

static inline size_t align256(size_t x) { return (x + 255) & ~(size_t)255; }

__device__ __forceinline__ unsigned short f2bf(float f) {
  unsigned int x = __float_as_uint(f);
  unsigned int r = x + 0x7fffu + ((x >> 16) & 1u);  // RNE
  return (unsigned short)(r >> 16);
}
__device__ __forceinline__ float bflo(unsigned int u) { return __uint_as_float(u << 16); }
__device__ __forceinline__ float bfhi(unsigned int u) { return __uint_as_float(u & 0xffff0000u); }

// ---------------- prep: XCD-sliced bucket build + goff + weight converts ----------------

__global__ __launch_bounds__(256) void k_prep(const int* __restrict__ src,
                                              const int* __restrict__ dst,
                                              int* __restrict__ cnt,
                                              int* __restrict__ bsrc, int E, int N,
                                              const float* __restrict__ W_comb,
                                              const float* __restrict__ gW1,
                                              const float* __restrict__ gW2,
                                              unsigned short* __restrict__ Wcb,
                                              unsigned short* __restrict__ W1b,
                                              unsigned short* __restrict__ W2b,
                                              const int* __restrict__ batch,
                                              int* __restrict__ goff, int G) {
  const int bid = blockIdx.x;
  const int tid = threadIdx.x;
  if (bid < NBK) {
    const int slice = bid & 7;
    const int sidx = bid >> 3;
    const int s_lo = (int)(((long long)slice * N) >> 3);
    const int s_hi = (int)(((long long)(slice + 1) * N) >> 3);
    for (int e = sidx * 256 + tid; e < E; e += (NBK / 8) * 256) {
      int d = dst[e];
      if (d >= s_lo && d < s_hi) {
        int slot = atomicAdd(&cnt[d], 1);
        if (slot < CAP) bsrc[(size_t)d * CAP + slot] = src[e];
      }
    }
  } else if (bid < NBK + 192) {
    int i = (bid - NBK) * 256 + tid;
    if (i < 128 * 256) Wcb[i] = f2bf(W_comb[i]);
    if (i < 3 * 128 * 128) {
      W1b[i] = f2bf(gW1[i]);
      W2b[i] = f2bf(gW2[i]);
    }
  } else {
    int g = (bid - NBK - 192) * 256 + tid;
    if (g <= G) {
      int lo = 0, hi = N;
      while (lo < hi) {
        int mid = (lo + hi) >> 1;
        if (batch[mid] < g) lo = mid + 1; else hi = mid;
      }
      goff[g] = lo;
    }
  }
}

// ---------------- fused init: [emb(z)||pos-proj] -> GEMM Wc(K=256) -> relu -> GEMM W1[0] ----

__global__ __launch_bounds__(256, 2) void k_init_mm(const int* __restrict__ z,
                                                    const float* __restrict__ pos,
                                                    const float* __restrict__ emb,
                                                    const float* __restrict__ W_pos,
                                                    const float* __restrict__ b_pos,
                                                    const unsigned short* __restrict__ Wcb,
                                                    const float* __restrict__ bias,
                                                    const unsigned short* __restrict__ W1n,
                                                    unsigned short* __restrict__ Y, int n) {
  __shared__ unsigned int sE[32 * 128];  // input rows (256 bf16), swizzled
  __shared__ unsigned int sB[32 * 64];   // intermediate x rows (128 bf16), swizzled
  const int t = threadIdx.x;
  const int w = t >> 6, l = t & 63, lr = l & 15, lk = l >> 4;

  bfrag wcf[2][8];
#pragma unroll
  for (int s = 0; s < 2; ++s)
#pragma unroll
    for (int ks = 0; ks < 8; ++ks)
      wcf[s][ks] = *(const bfrag*)(Wcb + (size_t)(32 * w + 16 * s + lr) * 256 + ks * 32 + lk * 8);
  bfrag w1f[2][4];
#pragma unroll
  for (int s = 0; s < 2; ++s)
#pragma unroll
    for (int ks = 0; ks < 4; ++ks)
      w1f[s][ks] = *(const bfrag*)(W1n + (size_t)(32 * w + 16 * s + lr) * HID + ks * 32 + lk * 8);
  const float bias0 = bias[32 * w + lr];
  const float bias1 = bias[32 * w + 16 + lr];

  const int m0 = blockIdx.x * 32;
  {
    const int r = t >> 3, i = t & 7;
    int node = m0 + r;
    if (node >= n) node = n - 1;
    const int zz = z[node];
    const float p0 = pos[node * 3 + 0], p1 = pos[node * 3 + 1], p2 = pos[node * 3 + 2];
    const int swz = (r & 7) << 2;
#pragma unroll
    for (int k = 0; k < 16; ++k) {
      const int j = i + k * 8;
      float v0, v1;
      if (j < 64) {
        const float2 ev = *(const float2*)&emb[(size_t)zz * 128 + 2 * j];
        v0 = ev.x; v1 = ev.y;
      } else {
        const int f0 = 2 * j - 128;
        v0 = b_pos[f0] + W_pos[f0 * 3] * p0 + W_pos[f0 * 3 + 1] * p1 + W_pos[f0 * 3 + 2] * p2;
        v1 = b_pos[f0 + 1] + W_pos[f0 * 3 + 3] * p0 + W_pos[f0 * 3 + 4] * p1 +
             W_pos[f0 * 3 + 5] * p2;
      }
      sE[r * 128 + (j ^ swz)] = (unsigned int)f2bf(v0) | ((unsigned int)f2bf(v1) << 16);
    }
  }
  __syncthreads();

  f32x4 acc00 = {0.f, 0.f, 0.f, 0.f}, acc01 = acc00, acc10 = acc00, acc11 = acc00;
#pragma unroll
  for (int mt = 0; mt < 2; ++mt) {
    const int row = 16 * mt + lr;
    const int swz = (row & 7) << 2;
#pragma unroll
    for (int ks = 0; ks < 8; ++ks) {
      const bfrag a = *(const bfrag*)&sE[row * 128 + ((ks * 16 + lk * 4) ^ swz)];
      if (mt == 0) {
        acc00 = __builtin_amdgcn_mfma_f32_16x16x32_bf16(a, wcf[0][ks], acc00, 0, 0, 0);
        acc01 = __builtin_amdgcn_mfma_f32_16x16x32_bf16(a, wcf[1][ks], acc01, 0, 0, 0);
      } else {
        acc10 = __builtin_amdgcn_mfma_f32_16x16x32_bf16(a, wcf[0][ks], acc10, 0, 0, 0);
        acc11 = __builtin_amdgcn_mfma_f32_16x16x32_bf16(a, wcf[1][ks], acc11, 0, 0, 0);
      }
    }
  }
  {
    unsigned short* sB16 = (unsigned short*)sB;
#pragma unroll
    for (int mt = 0; mt < 2; ++mt) {
#pragma unroll
      for (int s = 0; s < 2; ++s) {
        const f32x4 a = mt == 0 ? (s == 0 ? acc00 : acc01) : (s == 0 ? acc10 : acc11);
        const float bb = s == 0 ? bias0 : bias1;
        const int col = 32 * w + 16 * s + lr;
#pragma unroll
        for (int r = 0; r < 4; ++r) {
          const int rowL = 16 * mt + 4 * lk + r;
          const int cu = (col >> 1) ^ ((rowL & 7) << 2);
          sB16[rowL * 128 + cu * 2 + (col & 1)] = f2bf(fmaxf(a[r] + bb, 0.f));
        }
      }
    }
  }
  __syncthreads();

  f32x4 u00 = {0.f, 0.f, 0.f, 0.f}, u01 = u00, u10 = u00, u11 = u00;
#pragma unroll
  for (int mt = 0; mt < 2; ++mt) {
    const int row = 16 * mt + lr;
    const int swz = (row & 7) << 2;
#pragma unroll
    for (int ks = 0; ks < 4; ++ks) {
      const bfrag a = *(const bfrag*)&sB[row * 64 + ((ks * 16 + lk * 4) ^ swz)];
      if (mt == 0) {
        u00 = __builtin_amdgcn_mfma_f32_16x16x32_bf16(a, w1f[0][ks], u00, 0, 0, 0);
        u01 = __builtin_amdgcn_mfma_f32_16x16x32_bf16(a, w1f[1][ks], u01, 0, 0, 0);
      } else {
        u10 = __builtin_amdgcn_mfma_f32_16x16x32_bf16(a, w1f[0][ks], u10, 0, 0, 0);
        u11 = __builtin_amdgcn_mfma_f32_16x16x32_bf16(a, w1f[1][ks], u11, 0, 0, 0);
      }
    }
  }
#pragma unroll
  for (int mt = 0; mt < 2; ++mt) {
#pragma unroll
    for (int s = 0; s < 2; ++s) {
      const f32x4 a = mt == 0 ? (s == 0 ? u00 : u01) : (s == 0 ? u10 : u11);
      const int col = 32 * w + 16 * s + lr;
#pragma unroll
      for (int r = 0; r < 4; ++r) {
        const int row = m0 + 16 * mt + 4 * lk + r;
        if (row < n) Y[(size_t)row * HID + col] = f2bf(a[r]);
      }
    }
  }
}

// ---------------- fused layer: gather(u)+b1+relu -> GEMM W2(+b2,relu) -> GEMM W1next --------
// Phase A (paired-lane gather): lanes 0-31 process edge k, lanes 32-63 edge k+1;
// each lane loads uint2 (8B, 4 bf16 features); __shfl_xor(32) combines halves at row end.

template <int LAST>
__global__ __launch_bounds__(256, 2) void k_layer(const unsigned int* __restrict__ U,
                                                  const int* __restrict__ cnt,
                                                  const int* __restrict__ bsrc,
                                                  const float* __restrict__ b1,
                                                  const unsigned short* __restrict__ W2b,
                                                  const float* __restrict__ b2,
                                                  const unsigned short* __restrict__ W1n,
                                                  unsigned short* __restrict__ Y, int n) {
  __shared__ unsigned int sA[32 * 64];  // h rows (gathered, post-relu), swizzled
  __shared__ unsigned int sB[32 * 64];  // x rows (W2 output), swizzled
  const int t = threadIdx.x;
  const int w = t >> 6, l = t & 63, lr = l & 15, lk = l >> 4;
  const int h = l >> 5, q = l & 31;

  bfrag w2f[2][4];
#pragma unroll
  for (int s = 0; s < 2; ++s)
#pragma unroll
    for (int ks = 0; ks < 4; ++ks)
      w2f[s][ks] = *(const bfrag*)(W2b + (size_t)(32 * w + 16 * s + lr) * HID + ks * 32 + lk * 8);
  bfrag w1f[2][4];
  if (!LAST) {
#pragma unroll
    for (int s = 0; s < 2; ++s)
#pragma unroll
      for (int ks = 0; ks < 4; ++ks)
        w1f[s][ks] = *(const bfrag*)(W1n + (size_t)(32 * w + 16 * s + lr) * HID + ks * 32 + lk * 8);
  }
  const float b2a = b2[32 * w + lr];
  const float b2b = b2[32 * w + 16 + lr];
  const float4 b1v = *(const float4*)&b1[4 * q];  // features 4q..4q+3

  const int ntiles = (n + 31) >> 5;
  for (int tile = blockIdx.x; tile < ntiles; tile += gridDim.x) {
    const int m0 = tile * 32;
    // ---- phase A: gather 8 rows per wave, paired-lane dwordx2 ----
#pragma unroll 1
    for (int ri = 0; ri < 8; ++ri) {
      const int row = 8 * w + ri;
      int node = m0 + row;
      if (node >= n) node = n - 1;
      int deg = cnt[node];
      if (deg > CAP) deg = CAP;
      const int eidx = bsrc[(size_t)node * CAP + l];  // lane l = edge l's src
      float s0 = 0.f, s1 = 0.f, s2 = 0.f, s3 = 0.f;
      float t0 = 0.f, t1 = 0.f, t2 = 0.f, t3 = 0.f;
      int k = 0;
      for (; k + 3 < deg; k += 4) {
        const int ea = __shfl(eidx, k + h);
        const int eb = __shfl(eidx, k + 2 + h);
        const uint2 ua = *(const uint2*)(U + (size_t)ea * 64 + 2 * q);
        const uint2 ub = *(const uint2*)(U + (size_t)eb * 64 + 2 * q);
        s0 += bflo(ua.x); s1 += bfhi(ua.x); s2 += bflo(ua.y); s3 += bfhi(ua.y);
        t0 += bflo(ub.x); t1 += bfhi(ub.x); t2 += bflo(ub.y); t3 += bfhi(ub.y);
      }
      for (; k < deg; k += 2) {  // at most 2 iterations (<=3 leftover edges)
        const int kk = k + h;
        const int ea = __shfl(eidx, kk < deg ? kk : k);
        const uint2 ua = *(const uint2*)(U + (size_t)ea * 64 + 2 * q);
        const float m = kk < deg ? 1.f : 0.f;
        s0 += m * bflo(ua.x); s1 += m * bfhi(ua.x);
        s2 += m * bflo(ua.y); s3 += m * bfhi(ua.y);
      }
      float r0 = s0 + t0, r1 = s1 + t1, r2 = s2 + t2, r3 = s3 + t3;
      r0 += __shfl_xor(r0, 32);
      r1 += __shfl_xor(r1, 32);
      r2 += __shfl_xor(r2, 32);
      r3 += __shfl_xor(r3, 32);
      const uint2 us = *(const uint2*)(U + (size_t)node * 64 + 2 * q);  // self term
      r0 += bflo(us.x); r1 += bfhi(us.x); r2 += bflo(us.y); r3 += bfhi(us.y);
      if (h == 0) {
        const int swz = (row & 7) << 2;
        const unsigned int o0 = (unsigned int)f2bf(fmaxf(r0 + b1v.x, 0.f)) |
                                ((unsigned int)f2bf(fmaxf(r1 + b1v.y, 0.f)) << 16);
        const unsigned int o1 = (unsigned int)f2bf(fmaxf(r2 + b1v.z, 0.f)) |
                                ((unsigned int)f2bf(fmaxf(r3 + b1v.w, 0.f)) << 16);
        *(uint2*)&sA[row * 64 + ((2 * q) ^ swz)] = make_uint2(o0, o1);
      }
    }
    __syncthreads();

    // ---- phase B: GEMM W2 ----
    f32x4 acc00 = {0.f, 0.f, 0.f, 0.f}, acc01 = acc00, acc10 = acc00, acc11 = acc00;
#pragma unroll
    for (int mt = 0; mt < 2; ++mt) {
      const int row = 16 * mt + lr;
      const int swz = (row & 7) << 2;
#pragma unroll
      for (int ks = 0; ks < 4; ++ks) {
        const bfrag a = *(const bfrag*)&sA[row * 64 + ((ks * 16 + lk * 4) ^ swz)];
        if (mt == 0) {
          acc00 = __builtin_amdgcn_mfma_f32_16x16x32_bf16(a, w2f[0][ks], acc00, 0, 0, 0);
          acc01 = __builtin_amdgcn_mfma_f32_16x16x32_bf16(a, w2f[1][ks], acc01, 0, 0, 0);
        } else {
          acc10 = __builtin_amdgcn_mfma_f32_16x16x32_bf16(a, w2f[0][ks], acc10, 0, 0, 0);
          acc11 = __builtin_amdgcn_mfma_f32_16x16x32_bf16(a, w2f[1][ks], acc11, 0, 0, 0);
        }
      }
    }
    if (LAST) {
#pragma unroll
      for (int mt = 0; mt < 2; ++mt) {
#pragma unroll
        for (int s = 0; s < 2; ++s) {
          const f32x4 a = mt == 0 ? (s == 0 ? acc00 : acc01) : (s == 0 ? acc10 : acc11);
          const float bb = s == 0 ? b2a : b2b;
          const int col = 32 * w + 16 * s + lr;
#pragma unroll
          for (int r = 0; r < 4; ++r) {
            const int row = m0 + 16 * mt + 4 * lk + r;
            if (row < n) Y[(size_t)row * HID + col] = f2bf(a[r] + bb);
          }
        }
      }
      __syncthreads();
    } else {
      unsigned short* sB16 = (unsigned short*)sB;
#pragma unroll
      for (int mt = 0; mt < 2; ++mt) {
#pragma unroll
        for (int s = 0; s < 2; ++s) {
          const f32x4 a = mt == 0 ? (s == 0 ? acc00 : acc01) : (s == 0 ? acc10 : acc11);
          const float bb = s == 0 ? b2a : b2b;
          const int col = 32 * w + 16 * s + lr;
#pragma unroll
          for (int r = 0; r < 4; ++r) {
            const int rowL = 16 * mt + 4 * lk + r;
            const int cu = (col >> 1) ^ ((rowL & 7) << 2);
            sB16[rowL * 128 + cu * 2 + (col & 1)] = f2bf(fmaxf(a[r] + bb, 0.f));
          }
        }
      }
      __syncthreads();
      // ---- phase C: GEMM W1next, write u_{i+1} ----
      f32x4 u00 = {0.f, 0.f, 0.f, 0.f}, u01 = u00, u10 = u00, u11 = u00;
#pragma unroll
      for (int mt = 0; mt < 2; ++mt) {
        const int row = 16 * mt + lr;
        const int swz = (row & 7) << 2;
#pragma unroll
        for (int ks = 0; ks < 4; ++ks) {
          const bfrag a = *(const bfrag*)&sB[row * 64 + ((ks * 16 + lk * 4) ^ swz)];
          if (mt == 0) {
            u00 = __builtin_amdgcn_mfma_f32_16x16x32_bf16(a, w1f[0][ks], u00, 0, 0, 0);
            u01 = __builtin_amdgcn_mfma_f32_16x16x32_bf16(a, w1f[1][ks], u01, 0, 0, 0);
          } else {
            u10 = __builtin_amdgcn_mfma_f32_16x16x32_bf16(a, w1f[0][ks], u10, 0, 0, 0);
            u11 = __builtin_amdgcn_mfma_f32_16x16x32_bf16(a, w1f[1][ks], u11, 0, 0, 0);
          }
        }
      }
#pragma unroll
      for (int mt = 0; mt < 2; ++mt) {
#pragma unroll
        for (int s = 0; s < 2; ++s) {
          const f32x4 a = mt == 0 ? (s == 0 ? u00 : u01) : (s == 0 ? u10 : u11);
          const int col = 32 * w + 16 * s + lr;
#pragma unroll
          for (int r = 0; r < 4; ++r) {
            const int row = m0 + 16 * mt + 4 * lk + r;
            if (row < n) Y[(size_t)row * HID + col] = f2bf(a[r]);
          }
        }
      }
    }
  }
}

// ---------------- pooling + predict MLP ----------------

__global__ __launch_bounds__(128) void k_pool(const unsigned short* __restrict__ X,
                                              const int* __restrict__ goff,
                                              const float* __restrict__ Wp1,
                                              const float* __restrict__ bp1,
                                              const float* __restrict__ Wp2,
                                              const float* __restrict__ bp2,
                                              float* __restrict__ out, int G) {
  __shared__ float sg[HID];
  __shared__ float sred[HID];
  int g = blockIdx.x;
  int f = threadIdx.x;
  int n0 = goff[g], n1 = goff[g + 1];
  float c0 = 0.f, c1 = 0.f, c2 = 0.f, c3 = 0.f;
  int nn = n0;
  for (; nn + 3 < n1; nn += 4) {
    c0 += __uint_as_float((unsigned int)X[(size_t)nn * HID + f] << 16);
    c1 += __uint_as_float((unsigned int)X[(size_t)(nn + 1) * HID + f] << 16);
    c2 += __uint_as_float((unsigned int)X[(size_t)(nn + 2) * HID + f] << 16);
    c3 += __uint_as_float((unsigned int)X[(size_t)(nn + 3) * HID + f] << 16);
  }
  for (; nn < n1; ++nn) c0 += __uint_as_float((unsigned int)X[(size_t)nn * HID + f] << 16);
  sg[f] = (c0 + c1) + (c2 + c3);
  __syncthreads();
  float a0 = 0.f, a1 = 0.f, a2 = 0.f, a3 = 0.f;
#pragma unroll
  for (int k4 = 0; k4 < 32; ++k4) {
    float4 wv = *(const float4*)&Wp1[f * HID + k4 * 4];
    float4 xv = *(const float4*)&sg[k4 * 4];
    a0 += wv.x * xv.x; a1 += wv.y * xv.y; a2 += wv.z * xv.z; a3 += wv.w * xv.w;
  }
  float h = fmaxf(bp1[f] + ((a0 + a1) + (a2 + a3)), 0.f);
  sred[f] = Wp2[f] * h;
  __syncthreads();
  for (int s = 64; s > 0; s >>= 1) {
    if (f < s) sred[f] += sred[f + s];
    __syncthreads();
  }
  if (f == 0) out[g] = sred[0] + bp2[0];
}

// ---------------- launch ----------------

extern "C" void kernel_launch(void* const* d_in, const int* in_sizes, int n_in,
                              void* d_out, int out_size, void* d_ws, size_t ws_size,
                              hipStream_t stream) {
  const int*   z      = (const int*)d_in[0];
  const float* pos    = (const float*)d_in[1];
  const int*   ei     = (const int*)d_in[2];
  const int*   batch  = (const int*)d_in[3];
  const float* emb    = (const float*)d_in[4];
  const float* W_pos  = (const float*)d_in[5];
  const float* b_pos  = (const float*)d_in[6];
  const float* W_comb = (const float*)d_in[7];
  const float* b_comb = (const float*)d_in[8];
  const float* gW1    = (const float*)d_in[9];
  const float* gb1    = (const float*)d_in[10];
  const float* gW2    = (const float*)d_in[11];
  const float* gb2    = (const float*)d_in[12];
  const float* Wp1    = (const float*)d_in[13];
  const float* bp1    = (const float*)d_in[14];
  const float* Wp2    = (const float*)d_in[15];
  const float* bp2    = (const float*)d_in[16];
  float* out = (float*)d_out;

  const int N = in_sizes[0];
  const int E = in_sizes[2] / 2;
  const int G = out_size;
  const int* srcp = ei;
  const int* dstp = ei + E;

  char* w = (char*)d_ws;
  unsigned short* Ub  = (unsigned short*)w; w += align256((size_t)N * 128 * 2);
  unsigned short* Vb  = (unsigned short*)w; w += align256((size_t)N * 128 * 2);
  unsigned short* Wcb = (unsigned short*)w; w += align256((size_t)128 * 256 * 2);
  unsigned short* W1b = (unsigned short*)w; w += align256((size_t)3 * 128 * 128 * 2);
  unsigned short* W2b = (unsigned short*)w; w += align256((size_t)3 * 128 * 128 * 2);
  int* cnt  = (int*)w; w += align256((size_t)N * 4);
  int* bsrc = (int*)w; w += align256((size_t)N * CAP * 4);
  int* goff = (int*)w; w += align256((size_t)(G + 1) * 4);

  hipMemsetAsync(cnt, 0, (size_t)N * 4, stream);

  k_prep<<<NBK + 192 + 5, 256, 0, stream>>>(srcp, dstp, cnt, bsrc, E, N,
                                            W_comb, gW1, gW2, Wcb, W1b, W2b,
                                            batch, goff, G);

  // u1 = W1[0] @ relu(Wc @ [emb||pe] + bc)
  k_init_mm<<<(N + 31) / 32, 256, 0, stream>>>(z, pos, emb, W_pos, b_pos, Wcb, b_comb,
                                               W1b, Ub, N);

  // layer 0: u2
  k_layer<0><<<NBL, 256, 0, stream>>>((const unsigned int*)Ub, cnt, bsrc, gb1,
                                      W2b, gb2, W1b + (size_t)1 * 128 * 128, Vb, N);
  // layer 1: u3
  k_layer<0><<<NBL, 256, 0, stream>>>((const unsigned int*)Vb, cnt, bsrc, gb1 + 128,
                                      W2b + (size_t)1 * 128 * 128, gb2 + 128,
                                      W1b + (size_t)2 * 128 * 128, Ub, N);
  // layer 2: x3 (no relu, no W1next)
  k_layer<1><<<NBL, 256, 0, stream>>>((const unsigned int*)Ub, cnt, bsrc, gb1 + 256,
                                      W2b + (size_t)2 * 128 * 128, gb2 + 256,
                                      (const unsigned short*)nullptr, Vb, N);

  k_pool<<<G, HID, 0, stream>>>(Vb, goff, Wp1, bp1, Wp2, bp2, out, G);
}

// Round 8
// 500.231 us; speedup vs baseline: 1.0999x; 1.0999x over previous
//
#include <hip/hip_runtime.h>
#include <hip/hip_bf16.h>

#define HID 128
#define CAP 64   // bucket capacity: deg ~ Poisson(16), P(any node >= 64) ~ 1e-14
#define NBK 2048 // scatter blocks in k_prep
#define NBL 1563 // layer-kernel blocks: ceil(3125 tiles / 2)

typedef __attribute__((ext_vector_type(8))) short bfrag;   // 8 bf16 = 4 VGPR
typedef __attribute__((ext_vector_type(4))) float f32x4;

static inline size_t align256(size_t x) { return (x + 255) & ~(size_t)255; }

__device__ __forceinline__ unsigned short f2bf(float f) {
  unsigned int x = __float_as_uint(f);
  unsigned int r = x + 0x7fffu + ((x >> 16) & 1u);  // RNE
  return (unsigned short)(r >> 16);
}
__device__ __forceinline__ float bflo(unsigned int u) { return __uint_as_float(u << 16); }
__device__ __forceinline__ float bfhi(unsigned int u) { return __uint_as_float(u & 0xffff0000u); }

// ---------------- prep: XCD-sliced bucket build + goff + weight converts ----------------

__global__ __launch_bounds__(256) void k_prep(const int* __restrict__ src,
                                              const int* __restrict__ dst,
                                              int* __restrict__ cnt,
                                              int* __restrict__ bsrc, int E, int N,
                                              const float* __restrict__ W_comb,
                                              const float* __restrict__ gW1,
                                              const float* __restrict__ gW2,
                                              unsigned short* __restrict__ Wcb,
                                              unsigned short* __restrict__ W1b,
                                              unsigned short* __restrict__ W2b,
                                              const int* __restrict__ batch,
                                              int* __restrict__ goff, int G) {
  const int bid = blockIdx.x;
  const int tid = threadIdx.x;
  if (bid < NBK) {
    const int slice = bid & 7;
    const int sidx = bid >> 3;
    const int s_lo = (int)(((long long)slice * N) >> 3);
    const int s_hi = (int)(((long long)(slice + 1) * N) >> 3);
    for (int e = sidx * 256 + tid; e < E; e += (NBK / 8) * 256) {
      int d = dst[e];
      if (d >= s_lo && d < s_hi) {
        int slot = atomicAdd(&cnt[d], 1);
        if (slot < CAP) bsrc[(size_t)d * CAP + slot] = src[e];
      }
    }
  } else if (bid < NBK + 192) {
    int i = (bid - NBK) * 256 + tid;
    if (i < 128 * 256) Wcb[i] = f2bf(W_comb[i]);
    if (i < 3 * 128 * 128) {
      W1b[i] = f2bf(gW1[i]);
      W2b[i] = f2bf(gW2[i]);
    }
  } else {
    int g = (bid - NBK - 192) * 256 + tid;
    if (g <= G) {
      int lo = 0, hi = N;
      while (lo < hi) {
        int mid = (lo + hi) >> 1;
        if (batch[mid] < g) lo = mid + 1; else hi = mid;
      }
      goff[g] = lo;
    }
  }
}

// ---------------- fused init: [emb(z)||pos-proj] -> GEMM Wc(K=256) -> relu -> GEMM W1[0] ----

__global__ __launch_bounds__(256, 2) void k_init_mm(const int* __restrict__ z,
                                                    const float* __restrict__ pos,
                                                    const float* __restrict__ emb,
                                                    const float* __restrict__ W_pos,
                                                    const float* __restrict__ b_pos,
                                                    const unsigned short* __restrict__ Wcb,
                                                    const float* __restrict__ bias,
                                                    const unsigned short* __restrict__ W1n,
                                                    unsigned short* __restrict__ Y, int n) {
  __shared__ unsigned int sE[32 * 128];  // input rows (256 bf16), swizzled
  __shared__ unsigned int sB[32 * 64];   // intermediate x rows (128 bf16), swizzled
  const int t = threadIdx.x;
  const int w = t >> 6, l = t & 63, lr = l & 15, lk = l >> 4;

  bfrag wcf[2][8];
#pragma unroll
  for (int s = 0; s < 2; ++s)
#pragma unroll
    for (int ks = 0; ks < 8; ++ks)
      wcf[s][ks] = *(const bfrag*)(Wcb + (size_t)(32 * w + 16 * s + lr) * 256 + ks * 32 + lk * 8);
  bfrag w1f[2][4];
#pragma unroll
  for (int s = 0; s < 2; ++s)
#pragma unroll
    for (int ks = 0; ks < 4; ++ks)
      w1f[s][ks] = *(const bfrag*)(W1n + (size_t)(32 * w + 16 * s + lr) * HID + ks * 32 + lk * 8);
  const float bias0 = bias[32 * w + lr];
  const float bias1 = bias[32 * w + 16 + lr];

  const int m0 = blockIdx.x * 32;
  {
    const int r = t >> 3, i = t & 7;
    int node = m0 + r;
    if (node >= n) node = n - 1;
    const int zz = z[node];
    const float p0 = pos[node * 3 + 0], p1 = pos[node * 3 + 1], p2 = pos[node * 3 + 2];
    const int swz = (r & 7) << 2;
#pragma unroll
    for (int k = 0; k < 16; ++k) {
      const int j = i + k * 8;
      float v0, v1;
      if (j < 64) {
        const float2 ev = *(const float2*)&emb[(size_t)zz * 128 + 2 * j];
        v0 = ev.x; v1 = ev.y;
      } else {
        const int f0 = 2 * j - 128;
        v0 = b_pos[f0] + W_pos[f0 * 3] * p0 + W_pos[f0 * 3 + 1] * p1 + W_pos[f0 * 3 + 2] * p2;
        v1 = b_pos[f0 + 1] + W_pos[f0 * 3 + 3] * p0 + W_pos[f0 * 3 + 4] * p1 +
             W_pos[f0 * 3 + 5] * p2;
      }
      sE[r * 128 + (j ^ swz)] = (unsigned int)f2bf(v0) | ((unsigned int)f2bf(v1) << 16);
    }
  }
  __syncthreads();

  f32x4 acc00 = {0.f, 0.f, 0.f, 0.f}, acc01 = acc00, acc10 = acc00, acc11 = acc00;
#pragma unroll
  for (int mt = 0; mt < 2; ++mt) {
    const int row = 16 * mt + lr;
    const int swz = (row & 7) << 2;
#pragma unroll
    for (int ks = 0; ks < 8; ++ks) {
      const bfrag a = *(const bfrag*)&sE[row * 128 + ((ks * 16 + lk * 4) ^ swz)];
      if (mt == 0) {
        acc00 = __builtin_amdgcn_mfma_f32_16x16x32_bf16(a, wcf[0][ks], acc00, 0, 0, 0);
        acc01 = __builtin_amdgcn_mfma_f32_16x16x32_bf16(a, wcf[1][ks], acc01, 0, 0, 0);
      } else {
        acc10 = __builtin_amdgcn_mfma_f32_16x16x32_bf16(a, wcf[0][ks], acc10, 0, 0, 0);
        acc11 = __builtin_amdgcn_mfma_f32_16x16x32_bf16(a, wcf[1][ks], acc11, 0, 0, 0);
      }
    }
  }
  {
    unsigned short* sB16 = (unsigned short*)sB;
#pragma unroll
    for (int mt = 0; mt < 2; ++mt) {
#pragma unroll
      for (int s = 0; s < 2; ++s) {
        const f32x4 a = mt == 0 ? (s == 0 ? acc00 : acc01) : (s == 0 ? acc10 : acc11);
        const float bb = s == 0 ? bias0 : bias1;
        const int col = 32 * w + 16 * s + lr;
#pragma unroll
        for (int r = 0; r < 4; ++r) {
          const int rowL = 16 * mt + 4 * lk + r;
          const int cu = (col >> 1) ^ ((rowL & 7) << 2);
          sB16[rowL * 128 + cu * 2 + (col & 1)] = f2bf(fmaxf(a[r] + bb, 0.f));
        }
      }
    }
  }
  __syncthreads();

  f32x4 u00 = {0.f, 0.f, 0.f, 0.f}, u01 = u00, u10 = u00, u11 = u00;
#pragma unroll
  for (int mt = 0; mt < 2; ++mt) {
    const int row = 16 * mt + lr;
    const int swz = (row & 7) << 2;
#pragma unroll
    for (int ks = 0; ks < 4; ++ks) {
      const bfrag a = *(const bfrag*)&sB[row * 64 + ((ks * 16 + lk * 4) ^ swz)];
      if (mt == 0) {
        u00 = __builtin_amdgcn_mfma_f32_16x16x32_bf16(a, w1f[0][ks], u00, 0, 0, 0);
        u01 = __builtin_amdgcn_mfma_f32_16x16x32_bf16(a, w1f[1][ks], u01, 0, 0, 0);
      } else {
        u10 = __builtin_amdgcn_mfma_f32_16x16x32_bf16(a, w1f[0][ks], u10, 0, 0, 0);
        u11 = __builtin_amdgcn_mfma_f32_16x16x32_bf16(a, w1f[1][ks], u11, 0, 0, 0);
      }
    }
  }
#pragma unroll
  for (int mt = 0; mt < 2; ++mt) {
#pragma unroll
    for (int s = 0; s < 2; ++s) {
      const f32x4 a = mt == 0 ? (s == 0 ? u00 : u01) : (s == 0 ? u10 : u11);
      const int col = 32 * w + 16 * s + lr;
#pragma unroll
      for (int r = 0; r < 4; ++r) {
        const int row = m0 + 16 * mt + 4 * lk + r;
        if (row < n) Y[(size_t)row * HID + col] = f2bf(a[r]);
      }
    }
  }
}

// ---------------- fused layer: gather(u)+b1+relu -> GEMM W2(+b2,relu) -> GEMM W1next --------
// Phase A: round-5 proven gather (4 scalar chains, wave-uniform shfl, early-exit) with
// all 8 rows' cnt/bucket/self prefetched up front (static indices, full unroll).
// Single LDS buffer sM reused for h rows then x rows (extra sync between).

template <int LAST>
__global__ __launch_bounds__(256, 2) void k_layer(const unsigned int* __restrict__ U,
                                                  const int* __restrict__ cnt,
                                                  const int* __restrict__ bsrc,
                                                  const float* __restrict__ b1,
                                                  const unsigned short* __restrict__ W2b,
                                                  const float* __restrict__ b2,
                                                  const unsigned short* __restrict__ W1n,
                                                  unsigned short* __restrict__ Y, int n) {
  __shared__ unsigned int sM[32 * 64];  // h rows, then x rows (128 bf16/row), swizzled
  const int t = threadIdx.x;
  const int w = t >> 6, l = t & 63, lr = l & 15, lk = l >> 4;

  bfrag w2f[2][4];
#pragma unroll
  for (int s = 0; s < 2; ++s)
#pragma unroll
    for (int ks = 0; ks < 4; ++ks)
      w2f[s][ks] = *(const bfrag*)(W2b + (size_t)(32 * w + 16 * s + lr) * HID + ks * 32 + lk * 8);
  bfrag w1f[2][4];
  if (!LAST) {
#pragma unroll
    for (int s = 0; s < 2; ++s)
#pragma unroll
      for (int ks = 0; ks < 4; ++ks)
        w1f[s][ks] = *(const bfrag*)(W1n + (size_t)(32 * w + 16 * s + lr) * HID + ks * 32 + lk * 8);
  }
  const float b2a = b2[32 * w + lr];
  const float b2b = b2[32 * w + 16 + lr];
  const float2 b1v = *(const float2*)&b1[2 * l];  // features 2l, 2l+1

  const int ntiles = (n + 31) >> 5;
  for (int tile = blockIdx.x; tile < ntiles; tile += gridDim.x) {
    const int m0 = tile * 32;
    // ---- phase A prefetch: 24 independent loads in flight ----
    int degs[8];
    int eidxs[8];
    unsigned int selfs[8];
#pragma unroll
    for (int ri = 0; ri < 8; ++ri) {
      int node = m0 + 8 * w + ri;
      if (node >= n) node = n - 1;
      int d = cnt[node];
      degs[ri] = d > CAP ? CAP : d;
      eidxs[ri] = bsrc[(size_t)node * CAP + l];
      selfs[ri] = U[(size_t)node * 64 + l];
    }
    // ---- phase A: gather 8 rows per wave ----
#pragma unroll
    for (int ri = 0; ri < 8; ++ri) {
      const int row = 8 * w + ri;
      const int deg = degs[ri];
      const int eidx = eidxs[ri];
      float a0 = bflo(selfs[ri]), a1 = bfhi(selfs[ri]);
      float b0 = 0.f, b1_ = 0.f, c0 = 0.f, c1 = 0.f, d0 = 0.f, d1 = 0.f;
      int k = 0;
      for (; k + 3 < deg; k += 4) {
        const int s0 = __shfl(eidx, k), s1 = __shfl(eidx, k + 1);
        const int s2 = __shfl(eidx, k + 2), s3 = __shfl(eidx, k + 3);
        const unsigned int ua = U[(size_t)s0 * 64 + l];
        const unsigned int ub = U[(size_t)s1 * 64 + l];
        const unsigned int uc = U[(size_t)s2 * 64 + l];
        const unsigned int ud = U[(size_t)s3 * 64 + l];
        a0 += bflo(ua); a1 += bfhi(ua);
        b0 += bflo(ub); b1_ += bfhi(ub);
        c0 += bflo(uc); c1 += bfhi(uc);
        d0 += bflo(ud); d1 += bfhi(ud);
      }
      for (; k < deg; ++k) {
        const unsigned int ua = U[(size_t)__shfl(eidx, k) * 64 + l];
        a0 += bflo(ua); a1 += bfhi(ua);
      }
      const float r0 = (a0 + b0) + (c0 + d0);
      const float r1 = (a1 + b1_) + (c1 + d1);
      sM[row * 64 + (l ^ ((row & 7) << 2))] =
          (unsigned int)f2bf(fmaxf(r0 + b1v.x, 0.f)) |
          ((unsigned int)f2bf(fmaxf(r1 + b1v.y, 0.f)) << 16);
    }
    __syncthreads();

    // ---- phase B: GEMM W2 (reads sM = h) ----
    f32x4 acc00 = {0.f, 0.f, 0.f, 0.f}, acc01 = acc00, acc10 = acc00, acc11 = acc00;
#pragma unroll
    for (int mt = 0; mt < 2; ++mt) {
      const int row = 16 * mt + lr;
      const int swz = (row & 7) << 2;
#pragma unroll
      for (int ks = 0; ks < 4; ++ks) {
        const bfrag a = *(const bfrag*)&sM[row * 64 + ((ks * 16 + lk * 4) ^ swz)];
        if (mt == 0) {
          acc00 = __builtin_amdgcn_mfma_f32_16x16x32_bf16(a, w2f[0][ks], acc00, 0, 0, 0);
          acc01 = __builtin_amdgcn_mfma_f32_16x16x32_bf16(a, w2f[1][ks], acc01, 0, 0, 0);
        } else {
          acc10 = __builtin_amdgcn_mfma_f32_16x16x32_bf16(a, w2f[0][ks], acc10, 0, 0, 0);
          acc11 = __builtin_amdgcn_mfma_f32_16x16x32_bf16(a, w2f[1][ks], acc11, 0, 0, 0);
        }
      }
    }
    if (LAST) {
#pragma unroll
      for (int mt = 0; mt < 2; ++mt) {
#pragma unroll
        for (int s = 0; s < 2; ++s) {
          const f32x4 a = mt == 0 ? (s == 0 ? acc00 : acc01) : (s == 0 ? acc10 : acc11);
          const float bb = s == 0 ? b2a : b2b;
          const int col = 32 * w + 16 * s + lr;
#pragma unroll
          for (int r = 0; r < 4; ++r) {
            const int row = m0 + 16 * mt + 4 * lk + r;
            if (row < n) Y[(size_t)row * HID + col] = f2bf(a[r] + bb);
          }
        }
      }
      __syncthreads();
    } else {
      __syncthreads();  // all waves done reading h before overwrite
      unsigned short* sM16 = (unsigned short*)sM;
#pragma unroll
      for (int mt = 0; mt < 2; ++mt) {
#pragma unroll
        for (int s = 0; s < 2; ++s) {
          const f32x4 a = mt == 0 ? (s == 0 ? acc00 : acc01) : (s == 0 ? acc10 : acc11);
          const float bb = s == 0 ? b2a : b2b;
          const int col = 32 * w + 16 * s + lr;
#pragma unroll
          for (int r = 0; r < 4; ++r) {
            const int rowL = 16 * mt + 4 * lk + r;
            const int cu = (col >> 1) ^ ((rowL & 7) << 2);
            sM16[rowL * 128 + cu * 2 + (col & 1)] = f2bf(fmaxf(a[r] + bb, 0.f));
          }
        }
      }
      __syncthreads();
      // ---- phase C: GEMM W1next (reads sM = x), write u_{i+1} ----
      f32x4 u00 = {0.f, 0.f, 0.f, 0.f}, u01 = u00, u10 = u00, u11 = u00;
#pragma unroll
      for (int mt = 0; mt < 2; ++mt) {
        const int row = 16 * mt + lr;
        const int swz = (row & 7) << 2;
#pragma unroll
        for (int ks = 0; ks < 4; ++ks) {
          const bfrag a = *(const bfrag*)&sM[row * 64 + ((ks * 16 + lk * 4) ^ swz)];
          if (mt == 0) {
            u00 = __builtin_amdgcn_mfma_f32_16x16x32_bf16(a, w1f[0][ks], u00, 0, 0, 0);
            u01 = __builtin_amdgcn_mfma_f32_16x16x32_bf16(a, w1f[1][ks], u01, 0, 0, 0);
          } else {
            u10 = __builtin_amdgcn_mfma_f32_16x16x32_bf16(a, w1f[0][ks], u10, 0, 0, 0);
            u11 = __builtin_amdgcn_mfma_f32_16x16x32_bf16(a, w1f[1][ks], u11, 0, 0, 0);
          }
        }
      }
#pragma unroll
      for (int mt = 0; mt < 2; ++mt) {
#pragma unroll
        for (int s = 0; s < 2; ++s) {
          const f32x4 a = mt == 0 ? (s == 0 ? u00 : u01) : (s == 0 ? u10 : u11);
          const int col = 32 * w + 16 * s + lr;
#pragma unroll
          for (int r = 0; r < 4; ++r) {
            const int row = m0 + 16 * mt + 4 * lk + r;
            if (row < n) Y[(size_t)row * HID + col] = f2bf(a[r]);
          }
        }
      }
      __syncthreads();  // before next tile's phase-A overwrite of sM
    }
  }
}

// ---------------- pooling + predict MLP ----------------

__global__ __launch_bounds__(128) void k_pool(const unsigned short* __restrict__ X,
                                              const int* __restrict__ goff,
                                              const float* __restrict__ Wp1,
                                              const float* __restrict__ bp1,
                                              const float* __restrict__ Wp2,
                                              const float* __restrict__ bp2,
                                              float* __restrict__ out, int G) {
  __shared__ float sg[HID];
  __shared__ float sred[HID];
  int g = blockIdx.x;
  int f = threadIdx.x;
  int n0 = goff[g], n1 = goff[g + 1];
  float c0 = 0.f, c1 = 0.f, c2 = 0.f, c3 = 0.f;
  int nn = n0;
  for (; nn + 3 < n1; nn += 4) {
    c0 += __uint_as_float((unsigned int)X[(size_t)nn * HID + f] << 16);
    c1 += __uint_as_float((unsigned int)X[(size_t)(nn + 1) * HID + f] << 16);
    c2 += __uint_as_float((unsigned int)X[(size_t)(nn + 2) * HID + f] << 16);
    c3 += __uint_as_float((unsigned int)X[(size_t)(nn + 3) * HID + f] << 16);
  }
  for (; nn < n1; ++nn) c0 += __uint_as_float((unsigned int)X[(size_t)nn * HID + f] << 16);
  sg[f] = (c0 + c1) + (c2 + c3);
  __syncthreads();
  float a0 = 0.f, a1 = 0.f, a2 = 0.f, a3 = 0.f;
#pragma unroll
  for (int k4 = 0; k4 < 32; ++k4) {
    float4 wv = *(const float4*)&Wp1[f * HID + k4 * 4];
    float4 xv = *(const float4*)&sg[k4 * 4];
    a0 += wv.x * xv.x; a1 += wv.y * xv.y; a2 += wv.z * xv.z; a3 += wv.w * xv.w;
  }
  float h = fmaxf(bp1[f] + ((a0 + a1) + (a2 + a3)), 0.f);
  sred[f] = Wp2[f] * h;
  __syncthreads();
  for (int s = 64; s > 0; s >>= 1) {
    if (f < s) sred[f] += sred[f + s];
    __syncthreads();
  }
  if (f == 0) out[g] = sred[0] + bp2[0];
}

// ---------------- launch ----------------

extern "C" void kernel_launch(void* const* d_in, const int* in_sizes, int n_in,
                              void* d_out, int out_size, void* d_ws, size_t ws_size,
                              hipStream_t stream) {
  const int*   z      = (const int*)d_in[0];
  const float* pos    = (const float*)d_in[1];
  const int*   ei     = (const int*)d_in[2];
  const int*   batch  = (const int*)d_in[3];
  const float* emb    = (const float*)d_in[4];
  const float* W_pos  = (const float*)d_in[5];
  const float* b_pos  = (const float*)d_in[6];
  const float* W_comb = (const float*)d_in[7];
  const float* b_comb = (const float*)d_in[8];
  const float* gW1    = (const float*)d_in[9];
  const float* gb1    = (const float*)d_in[10];
  const float* gW2    = (const float*)d_in[11];
  const float* gb2    = (const float*)d_in[12];
  const float* Wp1    = (const float*)d_in[13];
  const float* bp1    = (const float*)d_in[14];
  const float* Wp2    = (const float*)d_in[15];
  const float* bp2    = (const float*)d_in[16];
  float* out = (float*)d_out;

  const int N = in_sizes[0];
  const int E = in_sizes[2] / 2;
  const int G = out_size;
  const int* srcp = ei;
  const int* dstp = ei + E;

  char* w = (char*)d_ws;
  unsigned short* Ub  = (unsigned short*)w; w += align256((size_t)N * 128 * 2);
  unsigned short* Vb  = (unsigned short*)w; w += align256((size_t)N * 128 * 2);
  unsigned short* Wcb = (unsigned short*)w; w += align256((size_t)128 * 256 * 2);
  unsigned short* W1b = (unsigned short*)w; w += align256((size_t)3 * 128 * 128 * 2);
  unsigned short* W2b = (unsigned short*)w; w += align256((size_t)3 * 128 * 128 * 2);
  int* cnt  = (int*)w; w += align256((size_t)N * 4);
  int* bsrc = (int*)w; w += align256((size_t)N * CAP * 4);
  int* goff = (int*)w; w += align256((size_t)(G + 1) * 4);

  hipMemsetAsync(cnt, 0, (size_t)N * 4, stream);

  k_prep<<<NBK + 192 + 5, 256, 0, stream>>>(srcp, dstp, cnt, bsrc, E, N,
                                            W_comb, gW1, gW2, Wcb, W1b, W2b,
                                            batch, goff, G);

  // u1 = W1[0] @ relu(Wc @ [emb||pe] + bc)
  k_init_mm<<<(N + 31) / 32, 256, 0, stream>>>(z, pos, emb, W_pos, b_pos, Wcb, b_comb,
                                               W1b, Ub, N);

  // layer 0: u2
  k_layer<0><<<NBL, 256, 0, stream>>>((const unsigned int*)Ub, cnt, bsrc, gb1,
                                      W2b, gb2, W1b + (size_t)1 * 128 * 128, Vb, N);
  // layer 1: u3
  k_layer<0><<<NBL, 256, 0, stream>>>((const unsigned int*)Vb, cnt, bsrc, gb1 + 128,
                                      W2b + (size_t)1 * 128 * 128, gb2 + 128,
                                      W1b + (size_t)2 * 128 * 128, Ub, N);
  // layer 2: x3 (no relu, no W1next)
  k_layer<1><<<NBL, 256, 0, stream>>>((const unsigned int*)Ub, cnt, bsrc, gb1 + 256,
                                      W2b + (size_t)2 * 128 * 128, gb2 + 256,
                                      (const unsigned short*)nullptr, Vb, N);

  k_pool<<<G, HID, 0, stream>>>(Vb, goff, Wp1, bp1, Wp2, bp2, out, G);
}

// Round 9
// 431.914 us; speedup vs baseline: 1.2739x; 1.1582x over previous
//
#include <hip/hip_runtime.h>
#include <hip/hip_bf16.h>

#define HID 128
#define CAP 64   // bucket capacity: deg ~ Poisson(16), P(any node >= 64) ~ 1e-14
#define NBK 2048 // scatter blocks in k_prep

typedef __attribute__((ext_vector_type(8))) short bfrag;   // 8 bf16 = 4 VGPR
typedef __attribute__((ext_vector_type(4))) float f32x4;

static inline size_t align256(size_t x) { return (x + 255) & ~(size_t)255; }

__device__ __forceinline__ unsigned short f2bf(float f) {
  unsigned int x = __float_as_uint(f);
  unsigned int r = x + 0x7fffu + ((x >> 16) & 1u);  // RNE
  return (unsigned short)(r >> 16);
}
__device__ __forceinline__ float bflo(unsigned int u) { return __uint_as_float(u << 16); }
__device__ __forceinline__ float bfhi(unsigned int u) { return __uint_as_float(u & 0xffff0000u); }

// ---------------- prep: XCD-sliced bucket build + goff + weight converts ----------------

__global__ __launch_bounds__(256) void k_prep(const int* __restrict__ src,
                                              const int* __restrict__ dst,
                                              int* __restrict__ cnt,
                                              int* __restrict__ bsrc, int E, int N,
                                              const float* __restrict__ W_comb,
                                              const float* __restrict__ gW1,
                                              const float* __restrict__ gW2,
                                              unsigned short* __restrict__ Wcb,
                                              unsigned short* __restrict__ W1b,
                                              unsigned short* __restrict__ W2b,
                                              const int* __restrict__ batch,
                                              int* __restrict__ goff, int G) {
  const int bid = blockIdx.x;
  const int tid = threadIdx.x;
  if (bid < NBK) {
    const int slice = bid & 7;
    const int sidx = bid >> 3;
    const int s_lo = (int)(((long long)slice * N) >> 3);
    const int s_hi = (int)(((long long)(slice + 1) * N) >> 3);
    for (int e = sidx * 256 + tid; e < E; e += (NBK / 8) * 256) {
      int d = dst[e];
      if (d >= s_lo && d < s_hi) {
        int slot = atomicAdd(&cnt[d], 1);
        if (slot < CAP) bsrc[(size_t)d * CAP + slot] = src[e];
      }
    }
  } else if (bid < NBK + 192) {
    int i = (bid - NBK) * 256 + tid;
    if (i < 128 * 256) Wcb[i] = f2bf(W_comb[i]);
    if (i < 3 * 128 * 128) {
      W1b[i] = f2bf(gW1[i]);
      W2b[i] = f2bf(gW2[i]);
    }
  } else {
    int g = (bid - NBK - 192) * 256 + tid;
    if (g <= G) {
      int lo = 0, hi = N;
      while (lo < hi) {
        int mid = (lo + hi) >> 1;
        if (batch[mid] < g) lo = mid + 1; else hi = mid;
      }
      goff[g] = lo;
    }
  }
}

// ---------------- fused init: [emb(z)||pos-proj] -> GEMM Wc(K=256) -> relu -> GEMM W1[0] ----

__global__ __launch_bounds__(256, 2) void k_init_mm(const int* __restrict__ z,
                                                    const float* __restrict__ pos,
                                                    const float* __restrict__ emb,
                                                    const float* __restrict__ W_pos,
                                                    const float* __restrict__ b_pos,
                                                    const unsigned short* __restrict__ Wcb,
                                                    const float* __restrict__ bias,
                                                    const unsigned short* __restrict__ W1n,
                                                    unsigned short* __restrict__ Y, int n) {
  __shared__ unsigned int sE[32 * 128];  // input rows (256 bf16), swizzled
  __shared__ unsigned int sB[32 * 64];   // intermediate x rows (128 bf16), swizzled
  const int t = threadIdx.x;
  const int w = t >> 6, l = t & 63, lr = l & 15, lk = l >> 4;

  bfrag wcf[2][8];
#pragma unroll
  for (int s = 0; s < 2; ++s)
#pragma unroll
    for (int ks = 0; ks < 8; ++ks)
      wcf[s][ks] = *(const bfrag*)(Wcb + (size_t)(32 * w + 16 * s + lr) * 256 + ks * 32 + lk * 8);
  bfrag w1f[2][4];
#pragma unroll
  for (int s = 0; s < 2; ++s)
#pragma unroll
    for (int ks = 0; ks < 4; ++ks)
      w1f[s][ks] = *(const bfrag*)(W1n + (size_t)(32 * w + 16 * s + lr) * HID + ks * 32 + lk * 8);
  const float bias0 = bias[32 * w + lr];
  const float bias1 = bias[32 * w + 16 + lr];

  const int m0 = blockIdx.x * 32;
  {
    const int r = t >> 3, i = t & 7;
    int node = m0 + r;
    if (node >= n) node = n - 1;
    const int zz = z[node];
    const float p0 = pos[node * 3 + 0], p1 = pos[node * 3 + 1], p2 = pos[node * 3 + 2];
    const int swz = (r & 7) << 2;
#pragma unroll
    for (int k = 0; k < 16; ++k) {
      const int j = i + k * 8;
      float v0, v1;
      if (j < 64) {
        const float2 ev = *(const float2*)&emb[(size_t)zz * 128 + 2 * j];
        v0 = ev.x; v1 = ev.y;
      } else {
        const int f0 = 2 * j - 128;
        v0 = b_pos[f0] + W_pos[f0 * 3] * p0 + W_pos[f0 * 3 + 1] * p1 + W_pos[f0 * 3 + 2] * p2;
        v1 = b_pos[f0 + 1] + W_pos[f0 * 3 + 3] * p0 + W_pos[f0 * 3 + 4] * p1 +
             W_pos[f0 * 3 + 5] * p2;
      }
      sE[r * 128 + (j ^ swz)] = (unsigned int)f2bf(v0) | ((unsigned int)f2bf(v1) << 16);
    }
  }
  __syncthreads();

  f32x4 acc00 = {0.f, 0.f, 0.f, 0.f}, acc01 = acc00, acc10 = acc00, acc11 = acc00;
#pragma unroll
  for (int mt = 0; mt < 2; ++mt) {
    const int row = 16 * mt + lr;
    const int swz = (row & 7) << 2;
#pragma unroll
    for (int ks = 0; ks < 8; ++ks) {
      const bfrag a = *(const bfrag*)&sE[row * 128 + ((ks * 16 + lk * 4) ^ swz)];
      if (mt == 0) {
        acc00 = __builtin_amdgcn_mfma_f32_16x16x32_bf16(a, wcf[0][ks], acc00, 0, 0, 0);
        acc01 = __builtin_amdgcn_mfma_f32_16x16x32_bf16(a, wcf[1][ks], acc01, 0, 0, 0);
      } else {
        acc10 = __builtin_amdgcn_mfma_f32_16x16x32_bf16(a, wcf[0][ks], acc10, 0, 0, 0);
        acc11 = __builtin_amdgcn_mfma_f32_16x16x32_bf16(a, wcf[1][ks], acc11, 0, 0, 0);
      }
    }
  }
  {
    unsigned short* sB16 = (unsigned short*)sB;
#pragma unroll
    for (int mt = 0; mt < 2; ++mt) {
#pragma unroll
      for (int s = 0; s < 2; ++s) {
        const f32x4 a = mt == 0 ? (s == 0 ? acc00 : acc01) : (s == 0 ? acc10 : acc11);
        const float bb = s == 0 ? bias0 : bias1;
        const int col = 32 * w + 16 * s + lr;
#pragma unroll
        for (int r = 0; r < 4; ++r) {
          const int rowL = 16 * mt + 4 * lk + r;
          const int cu = (col >> 1) ^ ((rowL & 7) << 2);
          sB16[rowL * 128 + cu * 2 + (col & 1)] = f2bf(fmaxf(a[r] + bb, 0.f));
        }
      }
    }
  }
  __syncthreads();

  f32x4 u00 = {0.f, 0.f, 0.f, 0.f}, u01 = u00, u10 = u00, u11 = u00;
#pragma unroll
  for (int mt = 0; mt < 2; ++mt) {
    const int row = 16 * mt + lr;
    const int swz = (row & 7) << 2;
#pragma unroll
    for (int ks = 0; ks < 4; ++ks) {
      const bfrag a = *(const bfrag*)&sB[row * 64 + ((ks * 16 + lk * 4) ^ swz)];
      if (mt == 0) {
        u00 = __builtin_amdgcn_mfma_f32_16x16x32_bf16(a, w1f[0][ks], u00, 0, 0, 0);
        u01 = __builtin_amdgcn_mfma_f32_16x16x32_bf16(a, w1f[1][ks], u01, 0, 0, 0);
      } else {
        u10 = __builtin_amdgcn_mfma_f32_16x16x32_bf16(a, w1f[0][ks], u10, 0, 0, 0);
        u11 = __builtin_amdgcn_mfma_f32_16x16x32_bf16(a, w1f[1][ks], u11, 0, 0, 0);
      }
    }
  }
#pragma unroll
  for (int mt = 0; mt < 2; ++mt) {
#pragma unroll
    for (int s = 0; s < 2; ++s) {
      const f32x4 a = mt == 0 ? (s == 0 ? u00 : u01) : (s == 0 ? u10 : u11);
      const int col = 32 * w + 16 * s + lr;
#pragma unroll
      for (int r = 0; r < 4; ++r) {
        const int row = m0 + 16 * mt + 4 * lk + r;
        if (row < n) Y[(size_t)row * HID + col] = f2bf(a[r]);
      }
    }
  }
}

// ---------------- fused layer: gather(u)+b1+relu -> GEMM W2(+b2,relu) -> GEMM W1next --------
// Phase A (uint4 4-edge gather): 16 lanes cover one 256B row; the wave's 4 lane-groups
// process 4 edges at once. 1 bpermute + 1 dwordx4 load per 4 edges; 2-unrolled body
// keeps 8 edges (2KB) in flight. Epilogue: shfl_xor(16,32) folds groups; group 0 writes.
// One tile per block (grid = ntiles); two LDS buffers; 2 barriers per block.

template <int LAST>
__global__ __launch_bounds__(256, 3) void k_layer(const unsigned int* __restrict__ U,
                                                  const int* __restrict__ cnt,
                                                  const int* __restrict__ bsrc,
                                                  const float* __restrict__ b1,
                                                  const unsigned short* __restrict__ W2b,
                                                  const float* __restrict__ b2,
                                                  const unsigned short* __restrict__ W1n,
                                                  unsigned short* __restrict__ Y, int n) {
  __shared__ unsigned int sA[32 * 64];  // h rows (gathered, post-relu), swizzled
  __shared__ unsigned int sB[32 * 64];  // x rows (W2 output), swizzled
  const int t = threadIdx.x;
  const int w = t >> 6, l = t & 63, lr = l & 15, lk = l >> 4;
  const int lgrp = lk, lpos = lr;  // gather aliases: group 0..3, position 0..15

  bfrag w2f[2][4];
#pragma unroll
  for (int s = 0; s < 2; ++s)
#pragma unroll
    for (int ks = 0; ks < 4; ++ks)
      w2f[s][ks] = *(const bfrag*)(W2b + (size_t)(32 * w + 16 * s + lr) * HID + ks * 32 + lk * 8);
  bfrag w1f[2][4];
  if (!LAST) {
#pragma unroll
    for (int s = 0; s < 2; ++s)
#pragma unroll
      for (int ks = 0; ks < 4; ++ks)
        w1f[s][ks] = *(const bfrag*)(W1n + (size_t)(32 * w + 16 * s + lr) * HID + ks * 32 + lk * 8);
  }
  const float b2a = b2[32 * w + lr];
  const float b2b = b2[32 * w + 16 + lr];
  const float4 bb0 = *(const float4*)&b1[8 * lpos];      // features 8p..8p+3
  const float4 bb1 = *(const float4*)&b1[8 * lpos + 4];  // features 8p+4..8p+7
  const float ms = (lgrp == 0) ? 1.f : 0.f;              // self-term gate

  const int m0 = blockIdx.x * 32;

  // ---- phase A prefetch: deg + bucket rows for all 8 rows ----
  int degs[8];
  int eidxs[8];
#pragma unroll
  for (int ri = 0; ri < 8; ++ri) {
    int node = m0 + 8 * w + ri;
    if (node >= n) node = n - 1;
    int d = cnt[node];
    degs[ri] = d > CAP ? CAP : d;
    eidxs[ri] = bsrc[(size_t)node * CAP + l];
  }
  // ---- phase A: gather 8 rows per wave, 4 edges at a time ----
#pragma unroll
  for (int ri = 0; ri < 8; ++ri) {
    const int row = 8 * w + ri;
    int node = m0 + row;
    if (node >= n) node = n - 1;
    const int deg = degs[ri];
    const int eidx = eidxs[ri];
    const uint4 sv = *(const uint4*)(U + (size_t)node * 64 + 4 * lpos);  // self row chunk
    float a0 = ms * bflo(sv.x), a1 = ms * bfhi(sv.x);
    float a2 = ms * bflo(sv.y), a3 = ms * bfhi(sv.y);
    float a4 = ms * bflo(sv.z), a5 = ms * bfhi(sv.z);
    float a6 = ms * bflo(sv.w), a7 = ms * bfhi(sv.w);
    int k = 0;
    for (; k + 7 < deg; k += 8) {  // 8 edges per iter, 2 loads in flight
      const int e0 = __shfl(eidx, k + lgrp);
      const int e1 = __shfl(eidx, k + 4 + lgrp);
      const uint4 u0 = *(const uint4*)(U + (size_t)e0 * 64 + 4 * lpos);
      const uint4 u1 = *(const uint4*)(U + (size_t)e1 * 64 + 4 * lpos);
      a0 += bflo(u0.x); a1 += bfhi(u0.x); a2 += bflo(u0.y); a3 += bfhi(u0.y);
      a4 += bflo(u0.z); a5 += bfhi(u0.z); a6 += bflo(u0.w); a7 += bfhi(u0.w);
      a0 += bflo(u1.x); a1 += bfhi(u1.x); a2 += bflo(u1.y); a3 += bfhi(u1.y);
      a4 += bflo(u1.z); a5 += bfhi(u1.z); a6 += bflo(u1.w); a7 += bfhi(u1.w);
    }
    for (; k < deg; k += 4) {  // masked tail (deg>=1 here since k<deg)
      int idx = k + lgrp;
      const float m = idx < deg ? 1.f : 0.f;
      if (idx >= deg) idx = deg - 1;
      const int e0 = __shfl(eidx, idx);
      const uint4 u0 = *(const uint4*)(U + (size_t)e0 * 64 + 4 * lpos);
      a0 += m * bflo(u0.x); a1 += m * bfhi(u0.x); a2 += m * bflo(u0.y); a3 += m * bfhi(u0.y);
      a4 += m * bflo(u0.z); a5 += m * bfhi(u0.z); a6 += m * bflo(u0.w); a7 += m * bfhi(u0.w);
    }
    // fold the 4 lane-groups
    a0 += __shfl_xor(a0, 16); a0 += __shfl_xor(a0, 32);
    a1 += __shfl_xor(a1, 16); a1 += __shfl_xor(a1, 32);
    a2 += __shfl_xor(a2, 16); a2 += __shfl_xor(a2, 32);
    a3 += __shfl_xor(a3, 16); a3 += __shfl_xor(a3, 32);
    a4 += __shfl_xor(a4, 16); a4 += __shfl_xor(a4, 32);
    a5 += __shfl_xor(a5, 16); a5 += __shfl_xor(a5, 32);
    a6 += __shfl_xor(a6, 16); a6 += __shfl_xor(a6, 32);
    a7 += __shfl_xor(a7, 16); a7 += __shfl_xor(a7, 32);
    if (lgrp == 0) {
      const int swz = (row & 7) << 2;
      uint4 o;
      o.x = (unsigned int)f2bf(fmaxf(a0 + bb0.x, 0.f)) |
            ((unsigned int)f2bf(fmaxf(a1 + bb0.y, 0.f)) << 16);
      o.y = (unsigned int)f2bf(fmaxf(a2 + bb0.z, 0.f)) |
            ((unsigned int)f2bf(fmaxf(a3 + bb0.w, 0.f)) << 16);
      o.z = (unsigned int)f2bf(fmaxf(a4 + bb1.x, 0.f)) |
            ((unsigned int)f2bf(fmaxf(a5 + bb1.y, 0.f)) << 16);
      o.w = (unsigned int)f2bf(fmaxf(a6 + bb1.z, 0.f)) |
            ((unsigned int)f2bf(fmaxf(a7 + bb1.w, 0.f)) << 16);
      *(uint4*)&sA[row * 64 + ((4 * lpos) ^ swz)] = o;
    }
  }
  __syncthreads();

  // ---- phase B: GEMM W2 (reads sA) ----
  f32x4 acc00 = {0.f, 0.f, 0.f, 0.f}, acc01 = acc00, acc10 = acc00, acc11 = acc00;
#pragma unroll
  for (int mt = 0; mt < 2; ++mt) {
    const int row = 16 * mt + lr;
    const int swz = (row & 7) << 2;
#pragma unroll
    for (int ks = 0; ks < 4; ++ks) {
      const bfrag a = *(const bfrag*)&sA[row * 64 + ((ks * 16 + lk * 4) ^ swz)];
      if (mt == 0) {
        acc00 = __builtin_amdgcn_mfma_f32_16x16x32_bf16(a, w2f[0][ks], acc00, 0, 0, 0);
        acc01 = __builtin_amdgcn_mfma_f32_16x16x32_bf16(a, w2f[1][ks], acc01, 0, 0, 0);
      } else {
        acc10 = __builtin_amdgcn_mfma_f32_16x16x32_bf16(a, w2f[0][ks], acc10, 0, 0, 0);
        acc11 = __builtin_amdgcn_mfma_f32_16x16x32_bf16(a, w2f[1][ks], acc11, 0, 0, 0);
      }
    }
  }
  if (LAST) {
#pragma unroll
    for (int mt = 0; mt < 2; ++mt) {
#pragma unroll
      for (int s = 0; s < 2; ++s) {
        const f32x4 a = mt == 0 ? (s == 0 ? acc00 : acc01) : (s == 0 ? acc10 : acc11);
        const float bb = s == 0 ? b2a : b2b;
        const int col = 32 * w + 16 * s + lr;
#pragma unroll
        for (int r = 0; r < 4; ++r) {
          const int row = m0 + 16 * mt + 4 * lk + r;
          if (row < n) Y[(size_t)row * HID + col] = f2bf(a[r] + bb);
        }
      }
    }
  } else {
    unsigned short* sB16 = (unsigned short*)sB;
#pragma unroll
    for (int mt = 0; mt < 2; ++mt) {
#pragma unroll
      for (int s = 0; s < 2; ++s) {
        const f32x4 a = mt == 0 ? (s == 0 ? acc00 : acc01) : (s == 0 ? acc10 : acc11);
        const float bb = s == 0 ? b2a : b2b;
        const int col = 32 * w + 16 * s + lr;
#pragma unroll
        for (int r = 0; r < 4; ++r) {
          const int rowL = 16 * mt + 4 * lk + r;
          const int cu = (col >> 1) ^ ((rowL & 7) << 2);
          sB16[rowL * 128 + cu * 2 + (col & 1)] = f2bf(fmaxf(a[r] + bb, 0.f));
        }
      }
    }
    __syncthreads();
    // ---- phase C: GEMM W1next (reads sB), write u_{i+1} ----
    f32x4 u00 = {0.f, 0.f, 0.f, 0.f}, u01 = u00, u10 = u00, u11 = u00;
#pragma unroll
    for (int mt = 0; mt < 2; ++mt) {
      const int row = 16 * mt + lr;
      const int swz = (row & 7) << 2;
#pragma unroll
      for (int ks = 0; ks < 4; ++ks) {
        const bfrag a = *(const bfrag*)&sB[row * 64 + ((ks * 16 + lk * 4) ^ swz)];
        if (mt == 0) {
          u00 = __builtin_amdgcn_mfma_f32_16x16x32_bf16(a, w1f[0][ks], u00, 0, 0, 0);
          u01 = __builtin_amdgcn_mfma_f32_16x16x32_bf16(a, w1f[1][ks], u01, 0, 0, 0);
        } else {
          u10 = __builtin_amdgcn_mfma_f32_16x16x32_bf16(a, w1f[0][ks], u10, 0, 0, 0);
          u11 = __builtin_amdgcn_mfma_f32_16x16x32_bf16(a, w1f[1][ks], u11, 0, 0, 0);
        }
      }
    }
#pragma unroll
    for (int mt = 0; mt < 2; ++mt) {
#pragma unroll
      for (int s = 0; s < 2; ++s) {
        const f32x4 a = mt == 0 ? (s == 0 ? u00 : u01) : (s == 0 ? u10 : u11);
        const int col = 32 * w + 16 * s + lr;
#pragma unroll
        for (int r = 0; r < 4; ++r) {
          const int row = m0 + 16 * mt + 4 * lk + r;
          if (row < n) Y[(size_t)row * HID + col] = f2bf(a[r]);
        }
      }
    }
  }
}

// ---------------- pooling + predict MLP ----------------

__global__ __launch_bounds__(128) void k_pool(const unsigned short* __restrict__ X,
                                              const int* __restrict__ goff,
                                              const float* __restrict__ Wp1,
                                              const float* __restrict__ bp1,
                                              const float* __restrict__ Wp2,
                                              const float* __restrict__ bp2,
                                              float* __restrict__ out, int G) {
  __shared__ float sg[HID];
  __shared__ float sred[HID];
  int g = blockIdx.x;
  int f = threadIdx.x;
  int n0 = goff[g], n1 = goff[g + 1];
  float c0 = 0.f, c1 = 0.f, c2 = 0.f, c3 = 0.f;
  int nn = n0;
  for (; nn + 3 < n1; nn += 4) {
    c0 += __uint_as_float((unsigned int)X[(size_t)nn * HID + f] << 16);
    c1 += __uint_as_float((unsigned int)X[(size_t)(nn + 1) * HID + f] << 16);
    c2 += __uint_as_float((unsigned int)X[(size_t)(nn + 2) * HID + f] << 16);
    c3 += __uint_as_float((unsigned int)X[(size_t)(nn + 3) * HID + f] << 16);
  }
  for (; nn < n1; ++nn) c0 += __uint_as_float((unsigned int)X[(size_t)nn * HID + f] << 16);
  sg[f] = (c0 + c1) + (c2 + c3);
  __syncthreads();
  float a0 = 0.f, a1 = 0.f, a2 = 0.f, a3 = 0.f;
#pragma unroll
  for (int k4 = 0; k4 < 32; ++k4) {
    float4 wv = *(const float4*)&Wp1[f * HID + k4 * 4];
    float4 xv = *(const float4*)&sg[k4 * 4];
    a0 += wv.x * xv.x; a1 += wv.y * xv.y; a2 += wv.z * xv.z; a3 += wv.w * xv.w;
  }
  float h = fmaxf(bp1[f] + ((a0 + a1) + (a2 + a3)), 0.f);
  sred[f] = Wp2[f] * h;
  __syncthreads();
  for (int s = 64; s > 0; s >>= 1) {
    if (f < s) sred[f] += sred[f + s];
    __syncthreads();
  }
  if (f == 0) out[g] = sred[0] + bp2[0];
}

// ---------------- launch ----------------

extern "C" void kernel_launch(void* const* d_in, const int* in_sizes, int n_in,
                              void* d_out, int out_size, void* d_ws, size_t ws_size,
                              hipStream_t stream) {
  const int*   z      = (const int*)d_in[0];
  const float* pos    = (const float*)d_in[1];
  const int*   ei     = (const int*)d_in[2];
  const int*   batch  = (const int*)d_in[3];
  const float* emb    = (const float*)d_in[4];
  const float* W_pos  = (const float*)d_in[5];
  const float* b_pos  = (const float*)d_in[6];
  const float* W_comb = (const float*)d_in[7];
  const float* b_comb = (const float*)d_in[8];
  const float* gW1    = (const float*)d_in[9];
  const float* gb1    = (const float*)d_in[10];
  const float* gW2    = (const float*)d_in[11];
  const float* gb2    = (const float*)d_in[12];
  const float* Wp1    = (const float*)d_in[13];
  const float* bp1    = (const float*)d_in[14];
  const float* Wp2    = (const float*)d_in[15];
  const float* bp2    = (const float*)d_in[16];
  float* out = (float*)d_out;

  const int N = in_sizes[0];
  const int E = in_sizes[2] / 2;
  const int G = out_size;
  const int* srcp = ei;
  const int* dstp = ei + E;
  const int ntiles = (N + 31) / 32;

  char* w = (char*)d_ws;
  unsigned short* Ub  = (unsigned short*)w; w += align256((size_t)N * 128 * 2);
  unsigned short* Vb  = (unsigned short*)w; w += align256((size_t)N * 128 * 2);
  unsigned short* Wcb = (unsigned short*)w; w += align256((size_t)128 * 256 * 2);
  unsigned short* W1b = (unsigned short*)w; w += align256((size_t)3 * 128 * 128 * 2);
  unsigned short* W2b = (unsigned short*)w; w += align256((size_t)3 * 128 * 128 * 2);
  int* cnt  = (int*)w; w += align256((size_t)N * 4);
  int* bsrc = (int*)w; w += align256((size_t)N * CAP * 4);
  int* goff = (int*)w; w += align256((size_t)(G + 1) * 4);

  hipMemsetAsync(cnt, 0, (size_t)N * 4, stream);

  k_prep<<<NBK + 192 + 5, 256, 0, stream>>>(srcp, dstp, cnt, bsrc, E, N,
                                            W_comb, gW1, gW2, Wcb, W1b, W2b,
                                            batch, goff, G);

  // u1 = W1[0] @ relu(Wc @ [emb||pe] + bc)
  k_init_mm<<<ntiles, 256, 0, stream>>>(z, pos, emb, W_pos, b_pos, Wcb, b_comb,
                                        W1b, Ub, N);

  // layer 0: u2
  k_layer<0><<<ntiles, 256, 0, stream>>>((const unsigned int*)Ub, cnt, bsrc, gb1,
                                         W2b, gb2, W1b + (size_t)1 * 128 * 128, Vb, N);
  // layer 1: u3
  k_layer<0><<<ntiles, 256, 0, stream>>>((const unsigned int*)Vb, cnt, bsrc, gb1 + 128,
                                         W2b + (size_t)1 * 128 * 128, gb2 + 128,
                                         W1b + (size_t)2 * 128 * 128, Ub, N);
  // layer 2: x3 (no relu, no W1next)
  k_layer<1><<<ntiles, 256, 0, stream>>>((const unsigned int*)Ub, cnt, bsrc, gb1 + 256,
                                         W2b + (size_t)2 * 128 * 128, gb2 + 256,
                                         (const unsigned short*)nullptr, Vb, N);

  k_pool<<<G, HID, 0, stream>>>(Vb, goff, Wp1, bp1, Wp2, bp2, out, G);
}